// Round 2
// 1443.741 us; speedup vs baseline: 1.1362x; 1.1362x over previous
//
#include <hip/hip_runtime.h>
#include <stdint.h>

typedef unsigned long long u64;

#define NROWS 32768   // B*T
#define DK    512
#define MM    1024

// ws byte offsets (total ~5.3 MB)
#define WS_ET    0u          // 2 * 512*1024 f32 transposed embedding halves
#define WS_SE    4194304u    // 2048 f32  (||e_m||^2 per modality)
#define WS_PH    4202496u    // 2*64*1024 f32 (pH accumulators)
#define WS_CNT   4726784u    // 2*64*1024 i32 (index counts per batch)
#define WS_IDX   5251072u    // 2*32768 i32 (argmin indices)
#define WS_SC    5513216u    // 4096 f32 (Scode 64x64)
#define WS_MODES 5529600u    // 128 i32

// ---------------- se[mod*1024+m] = sum_k E[m][mod*512+k]^2 ----------------
__global__ void k_se(const float* __restrict__ E, float* __restrict__ se) {
  int t = threadIdx.x;
  int row = blockIdx.x * 4 + (t >> 6);  // 2048 rows total
  int lane = t & 63;
  int mod = row >> 10, m = row & 1023;
  const float4* er = (const float4*)(E + (size_t)m * 1024 + mod * 512);
  float4 a = er[lane * 2], b = er[lane * 2 + 1];
  float s = a.x*a.x + a.y*a.y + a.z*a.z + a.w*a.w
          + b.x*b.x + b.y*b.y + b.z*b.z + b.w*b.w;
  #pragma unroll
  for (int o = 1; o < 64; o <<= 1) s += __shfl_xor(s, o, 64);
  if (lane == 0) se[row] = s;
}

// ---------------- Et[mod][k][m] = E[m][mod*512+k] (coalesced staging later) --
__global__ void k_transpose(const float* __restrict__ E, float* __restrict__ Et) {
  __shared__ float tile[32][33];
  int t = threadIdx.x;
  int kt = blockIdx.x & 15, mt = blockIdx.x >> 4, mod = blockIdx.y;
  int j = t & 31, i0 = t >> 5;
  for (int ii = i0; ii < 32; ii += 8)
    tile[ii][j] = E[(size_t)(mt*32 + ii) * 1024 + mod*512 + kt*32 + j];
  __syncthreads();
  int mm2 = t & 31, kx = t >> 5;
  for (int kk = kx; kk < 32; kk += 8)
    Et[(size_t)mod * 524288 + (size_t)(kt*32 + kk) * 1024 + mt*32 + mm2] = tile[mm2][kk];
}

// ---------------- fused distance GEMM + softmax-accumulate + argmin ----------
// block: 32 rows x 1024 cols, 256 threads (4 waves), thread tile 8 rows x 16 cols
// 2 blocks/CU (LDS-limited); F/L ratio 128 FMA / 96 B LDS per kk -> VALU-bound
__global__ __launch_bounds__(256, 2) void k_main(
    const float* __restrict__ vsem, const float* __restrict__ asem,
    const float* __restrict__ Et, const float* __restrict__ se,
    float* __restrict__ pH, int* __restrict__ cnt, int* __restrict__ idx)
{
  __shared__ float Bs[16][1024];
  __shared__ __align__(16) float As[16][36];
  __shared__ float pH_part[1024];
  __shared__ float sx_lds[32];

  const int t = threadIdx.x;
  const int mod = blockIdx.y;          // 0 = video, 1 = audio
  const int r0 = blockIdx.x * 32;
  const int rg = t >> 6, cg = t & 63;  // rg = wave id (rows rg*8..+7), cg = lane
  const float* x = mod ? asem : vsem;

  // ||x||^2 for the block's 32 rows (per-row math identical to prior version)
  {
    int r = t >> 4, kl = t & 15;       // r in 0..15, two passes cover 32 rows
    #pragma unroll
    for (int h = 0; h < 2; ++h) {
      const float* xr = x + (size_t)(r0 + r + h * 16) * DK;
      float s = 0.f;
      for (int k = kl; k < DK; k += 16) { float v = xr[k]; s = fmaf(v, v, s); }
      #pragma unroll
      for (int o = 1; o < 16; o <<= 1) s += __shfl_xor(s, o, 64);
      if (kl == 0) sx_lds[r + h * 16] = s;
    }
  }

  float acc[128];
  #pragma unroll
  for (int q = 0; q < 128; ++q) acc[q] = 0.f;

  for (int k0 = 0; k0 < DK; k0 += 16) {
    __syncthreads();
    {
      int akl = t & 15, ar = t >> 4;   // As[kk][r] = x[r0+r][k0+kk]
      As[akl][ar]      = x[(size_t)(r0 + ar) * DK + k0 + akl];
      As[akl][ar + 16] = x[(size_t)(r0 + ar + 16) * DK + k0 + akl];
    }
    #pragma unroll
    for (int kk = 0; kk < 16; ++kk)
      *(float4*)&Bs[kk][t * 4] =
          ((const float4*)(Et + (size_t)mod * 524288 + (size_t)(k0 + kk) * 1024))[t];
    __syncthreads();
    #pragma unroll
    for (int kk = 0; kk < 16; ++kk) {
      const float4 a0 = *(const float4*)&As[kk][rg * 8];
      const float4 a1 = *(const float4*)&As[kk][rg * 8 + 4];
      const float4 b0 = *(const float4*)&Bs[kk][cg * 4];
      const float4 b1 = *(const float4*)&Bs[kk][256 + cg * 4];
      const float4 b2 = *(const float4*)&Bs[kk][512 + cg * 4];
      const float4 b3 = *(const float4*)&Bs[kk][768 + cg * 4];
      #pragma unroll
      for (int rr = 0; rr < 8; ++rr) {
        const float av = rr == 0 ? a0.x : rr == 1 ? a0.y : rr == 2 ? a0.z :
                         rr == 3 ? a0.w : rr == 4 ? a1.x : rr == 5 ? a1.y :
                         rr == 6 ? a1.z : a1.w;
        float* ar = acc + rr * 16;
        ar[0] = fmaf(av, b0.x, ar[0]);  ar[1] = fmaf(av, b0.y, ar[1]);
        ar[2] = fmaf(av, b0.z, ar[2]);  ar[3] = fmaf(av, b0.w, ar[3]);
        ar[4] = fmaf(av, b1.x, ar[4]);  ar[5] = fmaf(av, b1.y, ar[5]);
        ar[6] = fmaf(av, b1.z, ar[6]);  ar[7] = fmaf(av, b1.w, ar[7]);
        ar[8] = fmaf(av, b2.x, ar[8]);  ar[9] = fmaf(av, b2.y, ar[9]);
        ar[10] = fmaf(av, b2.z, ar[10]); ar[11] = fmaf(av, b2.w, ar[11]);
        ar[12] = fmaf(av, b3.x, ar[12]); ar[13] = fmaf(av, b3.y, ar[13]);
        ar[14] = fmaf(av, b3.z, ar[14]); ar[15] = fmaf(av, b3.w, ar[15]);
      }
    }
  }

  // ---- epilogue: d = fl(se+sx) - fl(2*dot)  (mimics numpy's op order) ----
  float sxv[8];
  #pragma unroll
  for (int rr = 0; rr < 8; ++rr) sxv[rr] = sx_lds[rg * 8 + rr];
  const float* seB = se + mod * 1024;

  float rowsum[8] = {0.f, 0.f, 0.f, 0.f, 0.f, 0.f, 0.f, 0.f};
  u64 bk[8] = {~0ull, ~0ull, ~0ull, ~0ull, ~0ull, ~0ull, ~0ull, ~0ull};
  #pragma unroll
  for (int j = 0; j < 4; ++j)
    #pragma unroll
    for (int i = 0; i < 4; ++i) {
      const int m = j * 256 + cg * 4 + i;
      const float sem = seB[m];
      #pragma unroll
      for (int rr = 0; rr < 8; ++rr) {
        const float d = (sem + sxv[rr]) - 2.0f * acc[rr * 16 + j * 4 + i];
        const float s = sqrtf(fmaxf(d, 0.0f));
        const float ww = __expf(-s);            // all s in [20,25]: f32-safe
        acc[rr * 16 + j * 4 + i] = ww;          // overwrite acc with weight
        rowsum[rr] += ww;
        unsigned ub = __float_as_uint(d);       // total-order map for floats
        ub = (ub & 0x80000000u) ? ~ub : (ub | 0x80000000u);
        u64 key = ((u64)ub << 32) | (u64)(unsigned)m;  // tie -> smallest m
        bk[rr] = key < bk[rr] ? key : bk[rr];
      }
    }
  #pragma unroll
  for (int o = 1; o < 64; o <<= 1) {
    #pragma unroll
    for (int rr = 0; rr < 8; ++rr) {
      rowsum[rr] += __shfl_xor(rowsum[rr], o, 64);
      u64 ok = __shfl_xor(bk[rr], o, 64);
      bk[rr] = ok < bk[rr] ? ok : bk[rr];
    }
  }

  const int b = r0 >> 9;  // batch (32 rows never straddle a batch)
  if (cg == 0) {
    #pragma unroll
    for (int rr = 0; rr < 8; ++rr) {
      const int row = r0 + rg * 8 + rr;
      const int m = (int)(bk[rr] & 0xFFFFFFFFull);
      idx[mod * NROWS + row] = m;
      atomicAdd(&cnt[((mod * 64 + b) << 10) + m], 1);
    }
  }

  float inv[8];
  #pragma unroll
  for (int rr = 0; rr < 8; ++rr) inv[rr] = 1.0f / rowsum[rr];

  for (int q = t; q < 1024; q += 256) pH_part[q] = 0.f;
  __syncthreads();
  #pragma unroll
  for (int j = 0; j < 4; ++j)
    #pragma unroll
    for (int i = 0; i < 4; ++i) {
      const int m = j * 256 + cg * 4 + i;
      float v = 0.f;
      #pragma unroll
      for (int rr = 0; rr < 8; ++rr) v += acc[rr * 16 + j * 4 + i] * inv[rr];
      atomicAdd(&pH_part[m], v);
    }
  __syncthreads();
  for (int q = t; q < 1024; q += 256)
    atomicAdd(&pH[((mod * 64 + b) << 10) + q], pH_part[q] * (1.0f / 512.0f));
}

// ---------------- mode per (modality,batch): argmax count, first-index tie --
__global__ void k_modes(const int* __restrict__ cnt, int* __restrict__ modes) {
  __shared__ u64 red[4];
  int t = threadIdx.x;
  int mod = blockIdx.x >> 6, b = blockIdx.x & 63;
  const int* c = cnt + ((mod * 64 + b) << 10);
  u64 best = 0;
  for (int m = t; m < 1024; m += 256) {
    u64 key = ((u64)(unsigned)c[m] << 32) | (u64)(0xFFFFFFFFu - (unsigned)m);
    best = key > best ? key : best;
  }
  #pragma unroll
  for (int o = 1; o < 64; o <<= 1) { u64 ok = __shfl_xor(best, o, 64); best = ok > best ? ok : best; }
  if ((t & 63) == 0) red[t >> 6] = best;
  __syncthreads();
  if (t == 0) {
    #pragma unroll
    for (int q = 1; q < 4; ++q) best = red[q] > best ? red[q] : best;
    modes[mod * 64 + b] = (int)(0xFFFFFFFFu - (unsigned)(best & 0xFFFFFFFFull));
  }
}

__global__ void k_equal(const int* __restrict__ modes, float* __restrict__ out5) {
  int t = threadIdx.x;  // 64
  float e = (modes[t] == modes[64 + t]) ? 1.0f : 0.0f;
  #pragma unroll
  for (int o = 1; o < 64; o <<= 1) e += __shfl_xor(e, o, 64);
  if (t == 0) out5[0] = e;
}

// ---------------- Scode[i][j] = a_pH[i]·log(v_pH[j]+1e-10) + v_pH[i]·log(a_pH[j]+1e-10)
__global__ void k_scode(const float* __restrict__ pH, float* __restrict__ Sc) {
  int t = threadIdx.x;
  int i = blockIdx.x;
  int j = t >> 2, part = t & 3;
  const float* vH = pH;
  const float* aH = pH + 65536;
  const float* ai = aH + i * 1024;
  const float* vi = vH + i * 1024;
  const float* vj = vH + j * 1024;
  const float* aj = aH + j * 1024;
  float s = 0.f;
  for (int m = part * 256; m < part * 256 + 256; ++m)
    s += ai[m] * logf(vj[m] + 1e-10f) + vi[m] * logf(aj[m] + 1e-10f);
  s += __shfl_xor(s, 1, 64);
  s += __shfl_xor(s, 2, 64);
  if (part == 0) Sc[i * 64 + j] = s;
}

__global__ void k_lcmcm(const float* __restrict__ Sc, float* __restrict__ out4) {
  __shared__ float red[4];
  __shared__ float maxs_sh;
  int t = threadIdx.x;  // 256
  float mx = -3.402823466e38f;
  for (int q = t; q < 4096; q += 256) mx = fmaxf(mx, -Sc[q]);
  #pragma unroll
  for (int o = 1; o < 64; o <<= 1) mx = fmaxf(mx, __shfl_xor(mx, o, 64));
  if ((t & 63) == 0) red[t >> 6] = mx;
  __syncthreads();
  if (t == 0) maxs_sh = fmaxf(fmaxf(red[0], red[1]), fmaxf(red[2], red[3]));
  __syncthreads();
  float maxS = maxs_sh;
  if (t < 64) {
    float sum = 0.f, diag = 0.f;
    for (int j2 = 0; j2 < 64; ++j2) {
      float e = expf(Sc[t * 64 + j2] + maxS);
      sum += e;
      if (j2 == t) diag = e;
    }
    float li = logf(diag / (sum + 1e-5f));
    #pragma unroll
    for (int o = 1; o < 64; o <<= 1) li += __shfl_xor(li, o, 64);
    if (t == 0) out4[0] = -(li * (1.0f / 64.0f));
  }
}

// ---------------- gather outputs 0..3 ----------------
__global__ __launch_bounds__(256) void k_gather(
    const float* __restrict__ E, const float* __restrict__ vsem,
    const float* __restrict__ asem, const int* __restrict__ idx,
    float* __restrict__ out0, float* __restrict__ out1,
    float* __restrict__ out2, float* __restrict__ out3)
{
  int n = blockIdx.x, t = threadIdx.x;
  int iv = idx[n], ia = idx[NROWS + n];
  const float4* E4 = (const float4*)E;
  ((float4*)(out0 + (size_t)n * 1024))[t] = E4[iv * 256 + t];
  ((float4*)(out1 + (size_t)n * 1024))[t] = E4[ia * 256 + t];
  if (t < 128) {
    float4 q = E4[iv * 256 + t];                       // video_embedding cols [0,512)
    float4 xv = ((const float4*)(vsem + (size_t)n * 512))[t];
    float4 r;
    r.x = xv.x + (q.x - xv.x); r.y = xv.y + (q.y - xv.y);
    r.z = xv.z + (q.z - xv.z); r.w = xv.w + (q.w - xv.w);
    ((float4*)(out2 + (size_t)n * 512))[t] = r;
  } else {
    int u = t - 128;
    float4 q = E4[ia * 256 + 128 + u];                 // audio_embedding cols [512,1024)
    float4 xa = ((const float4*)(asem + (size_t)n * 512))[u];
    float4 r;
    r.x = xa.x + (q.x - xa.x); r.y = xa.y + (q.y - xa.y);
    r.z = xa.z + (q.z - xa.z); r.w = xa.w + (q.w - xa.w);
    ((float4*)(out3 + (size_t)n * 512))[u] = r;
  }
}

extern "C" void kernel_launch(void* const* d_in, const int* in_sizes, int n_in,
                              void* d_out, int out_size, void* d_ws, size_t ws_size,
                              hipStream_t stream) {
  const float* asem = (const float*)d_in[0];   // audio_semantic
  const float* vsem = (const float*)d_in[1];   // video_semantic
  const float* E    = (const float*)d_in[2];   // embedding (1024 x 1024)
  char* ws = (char*)d_ws;
  float* Et    = (float*)(ws + WS_ET);
  float* se    = (float*)(ws + WS_SE);
  float* pH    = (float*)(ws + WS_PH);
  int*   cnt   = (int*)(ws + WS_CNT);
  int*   idx   = (int*)(ws + WS_IDX);
  float* Sc    = (float*)(ws + WS_SC);
  int*   modes = (int*)(ws + WS_MODES);
  float* out = (float*)d_out;

  // zero pH + cnt (contiguous 1 MB)
  hipMemsetAsync(ws + WS_PH, 0, 1048576, stream);

  hipLaunchKernelGGL(k_se, dim3(512), dim3(256), 0, stream, E, se);
  hipLaunchKernelGGL(k_transpose, dim3(512, 2), dim3(256), 0, stream, E, Et);
  hipLaunchKernelGGL(k_main, dim3(1024, 2), dim3(256), 0, stream,
                     vsem, asem, Et, se, pH, cnt, idx);
  hipLaunchKernelGGL(k_modes, dim3(128), dim3(256), 0, stream, cnt, modes);
  hipLaunchKernelGGL(k_equal, dim3(1), dim3(64), 0, stream, modes,
                     out + 100663297ull);
  hipLaunchKernelGGL(k_scode, dim3(64), dim3(256), 0, stream, pH, Sc);
  hipLaunchKernelGGL(k_lcmcm, dim3(1), dim3(256), 0, stream, Sc,
                     out + 100663296ull);
  hipLaunchKernelGGL(k_gather, dim3(32768), dim3(256), 0, stream,
                     E, vsem, asem, idx,
                     out, out + 33554432ull, out + 67108864ull, out + 83886080ull);
}